// Round 5
// baseline (526.399 us; speedup 1.0000x reference)
//
#include <hip/hip_runtime.h>
#include <hip/hip_bf16.h>

// Block-sparse attention: B=2, S=4096, H=16, D=128, BS=64, LOCAL=8, GLOBAL=1.
// fp32 in/out, bf16 MFMA, flash online softmax (exp2 domain).
// Round 5: round-3 skeleton (256thr/2048wg, proven cache behavior) +
// all-LDS XOR swizzles (40960 B -> 4 blocks/CU) + improved Vt read swizzle.

typedef __bf16 bf16_t;
typedef bf16_t bf16x8 __attribute__((ext_vector_type(8)));
typedef bf16_t bf16x4 __attribute__((ext_vector_type(4)));
typedef float f32x4 __attribute__((ext_vector_type(4)));

#define BSZ 64
#define DIM 128
#define NH 16
#define SEQ 4096
#define ROWSTRIDE (NH * DIM)

// Kb: [64][128] bf16, A = row*256 + col*2. Fold row low-3 bits into chunk bits.
__device__ __forceinline__ uint32_t kb_swz(uint32_t A) {
    return A ^ (((A >> 8) & 7u) << 4);
}
// Vt: [128][64] bf16, A = d*128 + k*2. Fold d bits so PV read (lanes vary d)
// spreads over 8 chunk slots per 16-lane phase.
__device__ __forceinline__ uint32_t vt_swz(uint32_t A) {
    return A ^ (((A >> 9) & 7u) << 4) ^ (((A >> 8) & 1u) << 6);
}
// Pl: per-wave [16][64] bf16, A = row*128 + col*2. Fold row low-3 bits.
__device__ __forceinline__ uint32_t pl_swz(uint32_t A) {
    return A ^ (((A >> 7) & 7u) << 4);
}

__global__ __launch_bounds__(256, 4) void sparse_attn_kernel(
    const float* __restrict__ q, const float* __restrict__ k,
    const float* __restrict__ v, float* __restrict__ out)
{
    __shared__ __align__(16) bf16_t Kb[BSZ * DIM];      // 16384 B
    __shared__ __align__(16) bf16_t Vt[DIM * BSZ];      // 16384 B
    __shared__ __align__(16) bf16_t Pl[4 * 16 * 64];    //  8192 B  (total 40960)

    // XCD-aware swizzle: 2048 wgs, 8 XCDs -> contiguous 256-chunk per XCD.
    const int L  = ((blockIdx.x & 7) << 8) | (blockIdx.x >> 3);
    const int qi = L & 63;
    const int h  = (L >> 6) & 15;
    const int b  = L >> 10;

    const int tid  = threadIdx.x;
    const int wave = tid >> 6;
    const int lane = tid & 63;
    const int lr = lane & 15;
    const int lk = lane >> 4;
    const int k0 = lk * 8;

    const int sc4 = tid & 31;   // staging: float4 column 0..31
    const int sr  = tid >> 5;   // staging: row group 0..7

    const float scale2 = 0.12751649736230476f;  // (1/sqrt(128)) * log2(e)

    const size_t bh_off = ((size_t)b * SEQ * NH + (size_t)h) * DIM;
    const float* kbh = k + bh_off;
    const float* vbh = v + bh_off;

    // ---- Q fragments, pre-scaled (wave owns q rows [qi*64+wave*16, +16)) ----
    bf16x8 qf[4];
    {
        const float* qrow = q + bh_off + (size_t)(qi * 64 + wave * 16 + lr) * ROWSTRIDE;
        #pragma unroll
        for (int kk = 0; kk < 4; ++kk) {
            const float4 a0 = *(const float4*)(qrow + 32 * kk + k0);
            const float4 a1 = *(const float4*)(qrow + 32 * kk + k0 + 4);
            bf16x8 f;
            f[0] = (bf16_t)(a0.x * scale2); f[1] = (bf16_t)(a0.y * scale2);
            f[2] = (bf16_t)(a0.z * scale2); f[3] = (bf16_t)(a0.w * scale2);
            f[4] = (bf16_t)(a1.x * scale2); f[5] = (bf16_t)(a1.y * scale2);
            f[6] = (bf16_t)(a1.z * scale2); f[7] = (bf16_t)(a1.w * scale2);
            qf[kk] = f;
        }
    }

    f32x4 oacc[8];
    #pragma unroll
    for (int n = 0; n < 8; ++n) oacc[n] = (f32x4){0.f, 0.f, 0.f, 0.f};
    float mrun[4], lrun[4];
    #pragma unroll
    for (int r = 0; r < 4; ++r) { mrun[r] = -3.0e38f; lrun[r] = 0.f; }

    const int nnz = (qi < 8) ? (qi + 1) : 9;

    float4 kreg[8];   // K row (8i+sr), cols 4*sc4..+3
    float4 vreg[8];   // V row 4*(sr+8*T)+i, cols 4*sc4..+3

    #define LOAD_KV(jb)                                                           \
    {                                                                             \
        const float* kb_ = kbh + (size_t)((jb) * 64) * ROWSTRIDE + 4 * sc4;       \
        const float* vb_ = vbh + (size_t)((jb) * 64) * ROWSTRIDE + 4 * sc4;       \
        _Pragma("unroll")                                                         \
        for (int i = 0; i < 8; ++i)                                               \
            kreg[i] = *(const float4*)(kb_ + (size_t)(8 * i + sr) * ROWSTRIDE);   \
        _Pragma("unroll")                                                         \
        for (int T = 0; T < 2; ++T)                                               \
            _Pragma("unroll")                                                     \
            for (int i = 0; i < 4; ++i)                                           \
                vreg[T * 4 + i] = *(const float4*)(vb_ +                          \
                    (size_t)(4 * (sr + 8 * T) + i) * ROWSTRIDE);                  \
    }

    LOAD_KV(0);  // j_of(0) == 0 for every qi

    for (int t = 0; t < nnz; ++t) {
        const int j = (qi < 8) ? t : ((t == 0) ? 0 : (qi - 8 + t));

        // ---- regs -> LDS (waits on the prefetch loads) ----
        #pragma unroll
        for (int i = 0; i < 8; ++i) {
            const float4 t4 = kreg[i];
            bf16x4 c = {(bf16_t)t4.x, (bf16_t)t4.y, (bf16_t)t4.z, (bf16_t)t4.w};
            const uint32_t A = kb_swz((uint32_t)((8 * i + sr) * 256 + 8 * sc4));
            *(bf16x4*)((char*)Kb + A) = c;
        }
        #pragma unroll
        for (int T = 0; T < 2; ++T) {
            #pragma unroll
            for (int j2 = 0; j2 < 4; ++j2) {
                const int d = 4 * sc4 + j2;
                bf16x4 c = {(bf16_t)((const float*)&vreg[T * 4 + 0])[j2],
                            (bf16_t)((const float*)&vreg[T * 4 + 1])[j2],
                            (bf16_t)((const float*)&vreg[T * 4 + 2])[j2],
                            (bf16_t)((const float*)&vreg[T * 4 + 3])[j2]};
                const uint32_t A = vt_swz((uint32_t)(d * 128 + 8 * (sr + 8 * T)));
                *(bf16x4*)((char*)Vt + A) = c;
            }
        }
        __syncthreads();

        // ---- issue next block's loads (complete under compute below) ----
        if (t + 1 < nnz) {
            const int jn = (qi < 8) ? (t + 1) : (qi - 8 + t + 1);
            LOAD_KV(jn);
        }

        // ---- S = Q*K^T (16x64 per wave), already in exp2 domain ----
        f32x4 sacc[4];
        __builtin_amdgcn_s_setprio(1);
        #pragma unroll
        for (int n = 0; n < 4; ++n) {
            f32x4 a = (f32x4){0.f, 0.f, 0.f, 0.f};
            #pragma unroll
            for (int kk = 0; kk < 4; ++kk) {
                const uint32_t A = kb_swz((uint32_t)((16 * n + lr) * 256 + 64 * kk + 16 * lk));
                bf16x8 kf = *(const bf16x8*)((const char*)Kb + A);
                a = __builtin_amdgcn_mfma_f32_16x16x32_bf16(qf[kk], kf, a, 0, 0, 0);
            }
            sacc[n] = a;
        }
        __builtin_amdgcn_s_setprio(0);

        // ---- mask (diag only) + row max ----
        float vmax[4];
        #pragma unroll
        for (int r = 0; r < 4; ++r) vmax[r] = -3.0e38f;
        if (j == qi) {
            #pragma unroll
            for (int n = 0; n < 4; ++n)
                #pragma unroll
                for (int r = 0; r < 4; ++r) {
                    float s = sacc[n][r];
                    const int col  = 16 * n + lr;
                    const int rowq = wave * 16 + 4 * lk + r;
                    if (col > rowq) s = -1.0e30f;
                    sacc[n][r] = s;
                    vmax[r] = fmaxf(vmax[r], s);
                }
        } else {
            #pragma unroll
            for (int n = 0; n < 4; ++n)
                #pragma unroll
                for (int r = 0; r < 4; ++r)
                    vmax[r] = fmaxf(vmax[r], sacc[n][r]);
        }
        #pragma unroll
        for (int r = 0; r < 4; ++r) {
            float m = vmax[r];
            m = fmaxf(m, __shfl_xor(m, 1));
            m = fmaxf(m, __shfl_xor(m, 2));
            m = fmaxf(m, __shfl_xor(m, 4));
            m = fmaxf(m, __shfl_xor(m, 8));
            vmax[r] = m;
        }

        // ---- online softmax (defer-max, THR=8 log2) ----
        bool defer = true;
        #pragma unroll
        for (int r = 0; r < 4; ++r) defer &= (vmax[r] - mrun[r] <= 8.0f);
        if (!__all(defer)) {
            #pragma unroll
            for (int r = 0; r < 4; ++r) {
                const float mnew = fmaxf(mrun[r], vmax[r]);
                const float alpha = exp2f(mrun[r] - mnew);
                mrun[r] = mnew;
                lrun[r] *= alpha;
                #pragma unroll
                for (int n = 0; n < 8; ++n) oacc[n][r] *= alpha;
            }
        }
        float rowsum[4];
        #pragma unroll
        for (int r = 0; r < 4; ++r) rowsum[r] = 0.f;
        #pragma unroll
        for (int n = 0; n < 4; ++n) {
            #pragma unroll
            for (int r = 0; r < 4; ++r) {
                const float p = exp2f(sacc[n][r] - mrun[r]);
                rowsum[r] += p;
                const uint32_t A = pl_swz((uint32_t)((4 * lk + r) * 128 + (16 * n + lr) * 2));
                *(bf16_t*)((char*)Pl + wave * 2048 + A) = (bf16_t)p;
            }
        }
        #pragma unroll
        for (int r = 0; r < 4; ++r) {
            float s = rowsum[r];
            s += __shfl_xor(s, 1);
            s += __shfl_xor(s, 2);
            s += __shfl_xor(s, 4);
            s += __shfl_xor(s, 8);
            lrun[r] += s;
        }

        // ---- O += P * V ----
        __builtin_amdgcn_s_setprio(1);
        #pragma unroll
        for (int n = 0; n < 8; ++n) {
            f32x4 a = oacc[n];
            #pragma unroll
            for (int kk = 0; kk < 2; ++kk) {
                const uint32_t Ap = pl_swz((uint32_t)(lr * 128 + (32 * kk + k0) * 2));
                bf16x8 pf = *(const bf16x8*)((const char*)Pl + wave * 2048 + Ap);
                const uint32_t Av = vt_swz((uint32_t)((16 * n + lr) * 128 + 64 * kk + 16 * lk));
                bf16x8 vf = *(const bf16x8*)((const char*)Vt + Av);
                a = __builtin_amdgcn_mfma_f32_16x16x32_bf16(pf, vf, a, 0, 0, 0);
            }
            oacc[n] = a;
        }
        __builtin_amdgcn_s_setprio(0);
        __syncthreads();
    }

    // ---- epilogue ----
    float* obase = out + bh_off + (size_t)(qi * 64 + wave * 16) * ROWSTRIDE;
    #pragma unroll
    for (int r = 0; r < 4; ++r) {
        const float inv = 1.0f / lrun[r];
        float* orow = obase + (size_t)(4 * lk + r) * ROWSTRIDE;
        #pragma unroll
        for (int n = 0; n < 8; ++n) {
            orow[16 * n + lr] = oacc[n][r] * inv;
        }
    }
}

extern "C" void kernel_launch(void* const* d_in, const int* in_sizes, int n_in,
                              void* d_out, int out_size, void* d_ws, size_t ws_size,
                              hipStream_t stream) {
    const float* q = (const float*)d_in[0];
    const float* k = (const float*)d_in[1];
    const float* v = (const float*)d_in[2];
    float* out = (float*)d_out;
    sparse_attn_kernel<<<dim3(2048), dim3(256), 0, stream>>>(q, k, v, out);
}

// Round 6
// 192.538 us; speedup vs baseline: 2.7340x; 2.7340x over previous
//
#include <hip/hip_runtime.h>
#include <hip/hip_bf16.h>

// Block-sparse attention: B=2, S=4096, H=16, D=128, BS=64, LOCAL=8, GLOBAL=1.
// fp32 in/out, bf16 MFMA, flash online softmax (exp2 domain).
// Round 6: round-5 body, but plain __launch_bounds__(256) — the (256,4)
// min-waves clamp forced VGPR=64 and spilled ~1.9GB to scratch (round-5
// FETCH/WRITE counters). LDS stays 40960 B (= 160KiB/4).

typedef __bf16 bf16_t;
typedef bf16_t bf16x8 __attribute__((ext_vector_type(8)));
typedef bf16_t bf16x4 __attribute__((ext_vector_type(4)));
typedef float f32x4 __attribute__((ext_vector_type(4)));

#define BSZ 64
#define DIM 128
#define NH 16
#define SEQ 4096
#define ROWSTRIDE (NH * DIM)

// Kb: [64][128] bf16, A = row*256 + col*2. Fold row low-3 bits into chunk bits.
__device__ __forceinline__ uint32_t kb_swz(uint32_t A) {
    return A ^ (((A >> 8) & 7u) << 4);
}
// Vt: [128][64] bf16, A = d*128 + k*2. Fold d bits so PV read (lanes vary d)
// spreads over 8 chunk slots per 16-lane phase.
__device__ __forceinline__ uint32_t vt_swz(uint32_t A) {
    return A ^ (((A >> 9) & 7u) << 4) ^ (((A >> 8) & 1u) << 6);
}
// Pl: per-wave [16][64] bf16, A = row*128 + col*2. Fold row low-3 bits.
__device__ __forceinline__ uint32_t pl_swz(uint32_t A) {
    return A ^ (((A >> 7) & 7u) << 4);
}

__global__ __launch_bounds__(256) void sparse_attn_kernel(
    const float* __restrict__ q, const float* __restrict__ k,
    const float* __restrict__ v, float* __restrict__ out)
{
    __shared__ __align__(16) bf16_t Kb[BSZ * DIM];      // 16384 B
    __shared__ __align__(16) bf16_t Vt[DIM * BSZ];      // 16384 B
    __shared__ __align__(16) bf16_t Pl[4 * 16 * 64];    //  8192 B  (total 40960)

    // XCD-aware swizzle: 2048 wgs, 8 XCDs -> contiguous 256-chunk per XCD.
    const int L  = ((blockIdx.x & 7) << 8) | (blockIdx.x >> 3);
    const int qi = L & 63;
    const int h  = (L >> 6) & 15;
    const int b  = L >> 10;

    const int tid  = threadIdx.x;
    const int wave = tid >> 6;
    const int lane = tid & 63;
    const int lr = lane & 15;
    const int lk = lane >> 4;
    const int k0 = lk * 8;

    const int sc4 = tid & 31;   // staging: float4 column 0..31
    const int sr  = tid >> 5;   // staging: row group 0..7

    const float scale2 = 0.12751649736230476f;  // (1/sqrt(128)) * log2(e)

    const size_t bh_off = ((size_t)b * SEQ * NH + (size_t)h) * DIM;
    const float* kbh = k + bh_off;
    const float* vbh = v + bh_off;

    // ---- Q fragments, pre-scaled (wave owns q rows [qi*64+wave*16, +16)) ----
    bf16x8 qf[4];
    {
        const float* qrow = q + bh_off + (size_t)(qi * 64 + wave * 16 + lr) * ROWSTRIDE;
        #pragma unroll
        for (int kk = 0; kk < 4; ++kk) {
            const float4 a0 = *(const float4*)(qrow + 32 * kk + k0);
            const float4 a1 = *(const float4*)(qrow + 32 * kk + k0 + 4);
            bf16x8 f;
            f[0] = (bf16_t)(a0.x * scale2); f[1] = (bf16_t)(a0.y * scale2);
            f[2] = (bf16_t)(a0.z * scale2); f[3] = (bf16_t)(a0.w * scale2);
            f[4] = (bf16_t)(a1.x * scale2); f[5] = (bf16_t)(a1.y * scale2);
            f[6] = (bf16_t)(a1.z * scale2); f[7] = (bf16_t)(a1.w * scale2);
            qf[kk] = f;
        }
    }

    f32x4 oacc[8];
    #pragma unroll
    for (int n = 0; n < 8; ++n) oacc[n] = (f32x4){0.f, 0.f, 0.f, 0.f};
    float mrun[4], lrun[4];
    #pragma unroll
    for (int r = 0; r < 4; ++r) { mrun[r] = -3.0e38f; lrun[r] = 0.f; }

    const int nnz = (qi < 8) ? (qi + 1) : 9;

    float4 kreg[8];   // K row (8i+sr), cols 4*sc4..+3
    float4 vreg[8];   // V row 4*(sr+8*T)+i, cols 4*sc4..+3

    #define LOAD_KV(jb)                                                           \
    {                                                                             \
        const float* kb_ = kbh + (size_t)((jb) * 64) * ROWSTRIDE + 4 * sc4;       \
        const float* vb_ = vbh + (size_t)((jb) * 64) * ROWSTRIDE + 4 * sc4;       \
        _Pragma("unroll")                                                         \
        for (int i = 0; i < 8; ++i)                                               \
            kreg[i] = *(const float4*)(kb_ + (size_t)(8 * i + sr) * ROWSTRIDE);   \
        _Pragma("unroll")                                                         \
        for (int T = 0; T < 2; ++T)                                               \
            _Pragma("unroll")                                                     \
            for (int i = 0; i < 4; ++i)                                           \
                vreg[T * 4 + i] = *(const float4*)(vb_ +                          \
                    (size_t)(4 * (sr + 8 * T) + i) * ROWSTRIDE);                  \
    }

    LOAD_KV(0);  // j_of(0) == 0 for every qi

    for (int t = 0; t < nnz; ++t) {
        const int j = (qi < 8) ? t : ((t == 0) ? 0 : (qi - 8 + t));

        // ---- regs -> LDS (waits on the prefetch loads) ----
        #pragma unroll
        for (int i = 0; i < 8; ++i) {
            const float4 t4 = kreg[i];
            bf16x4 c = {(bf16_t)t4.x, (bf16_t)t4.y, (bf16_t)t4.z, (bf16_t)t4.w};
            const uint32_t A = kb_swz((uint32_t)((8 * i + sr) * 256 + 8 * sc4));
            *(bf16x4*)((char*)Kb + A) = c;
        }
        #pragma unroll
        for (int T = 0; T < 2; ++T) {
            #pragma unroll
            for (int j2 = 0; j2 < 4; ++j2) {
                const int d = 4 * sc4 + j2;
                bf16x4 c = {(bf16_t)((const float*)&vreg[T * 4 + 0])[j2],
                            (bf16_t)((const float*)&vreg[T * 4 + 1])[j2],
                            (bf16_t)((const float*)&vreg[T * 4 + 2])[j2],
                            (bf16_t)((const float*)&vreg[T * 4 + 3])[j2]};
                const uint32_t A = vt_swz((uint32_t)(d * 128 + 8 * (sr + 8 * T)));
                *(bf16x4*)((char*)Vt + A) = c;
            }
        }
        __syncthreads();

        // ---- issue next block's loads (complete under compute below) ----
        if (t + 1 < nnz) {
            const int jn = (qi < 8) ? (t + 1) : (qi - 8 + t + 1);
            LOAD_KV(jn);
        }

        // ---- S = Q*K^T (16x64 per wave), already in exp2 domain ----
        f32x4 sacc[4];
        __builtin_amdgcn_s_setprio(1);
        #pragma unroll
        for (int n = 0; n < 4; ++n) {
            f32x4 a = (f32x4){0.f, 0.f, 0.f, 0.f};
            #pragma unroll
            for (int kk = 0; kk < 4; ++kk) {
                const uint32_t A = kb_swz((uint32_t)((16 * n + lr) * 256 + 64 * kk + 16 * lk));
                bf16x8 kf = *(const bf16x8*)((const char*)Kb + A);
                a = __builtin_amdgcn_mfma_f32_16x16x32_bf16(qf[kk], kf, a, 0, 0, 0);
            }
            sacc[n] = a;
        }
        __builtin_amdgcn_s_setprio(0);

        // ---- mask (diag only) + row max ----
        float vmax[4];
        #pragma unroll
        for (int r = 0; r < 4; ++r) vmax[r] = -3.0e38f;
        if (j == qi) {
            #pragma unroll
            for (int n = 0; n < 4; ++n)
                #pragma unroll
                for (int r = 0; r < 4; ++r) {
                    float s = sacc[n][r];
                    const int col  = 16 * n + lr;
                    const int rowq = wave * 16 + 4 * lk + r;
                    if (col > rowq) s = -1.0e30f;
                    sacc[n][r] = s;
                    vmax[r] = fmaxf(vmax[r], s);
                }
        } else {
            #pragma unroll
            for (int n = 0; n < 4; ++n)
                #pragma unroll
                for (int r = 0; r < 4; ++r)
                    vmax[r] = fmaxf(vmax[r], sacc[n][r]);
        }
        #pragma unroll
        for (int r = 0; r < 4; ++r) {
            float m = vmax[r];
            m = fmaxf(m, __shfl_xor(m, 1));
            m = fmaxf(m, __shfl_xor(m, 2));
            m = fmaxf(m, __shfl_xor(m, 4));
            m = fmaxf(m, __shfl_xor(m, 8));
            vmax[r] = m;
        }

        // ---- online softmax (defer-max, THR=8 log2) ----
        bool defer = true;
        #pragma unroll
        for (int r = 0; r < 4; ++r) defer &= (vmax[r] - mrun[r] <= 8.0f);
        if (!__all(defer)) {
            #pragma unroll
            for (int r = 0; r < 4; ++r) {
                const float mnew = fmaxf(mrun[r], vmax[r]);
                const float alpha = exp2f(mrun[r] - mnew);
                mrun[r] = mnew;
                lrun[r] *= alpha;
                #pragma unroll
                for (int n = 0; n < 8; ++n) oacc[n][r] *= alpha;
            }
        }
        float rowsum[4];
        #pragma unroll
        for (int r = 0; r < 4; ++r) rowsum[r] = 0.f;
        #pragma unroll
        for (int n = 0; n < 4; ++n) {
            #pragma unroll
            for (int r = 0; r < 4; ++r) {
                const float p = exp2f(sacc[n][r] - mrun[r]);
                rowsum[r] += p;
                const uint32_t A = pl_swz((uint32_t)((4 * lk + r) * 128 + (16 * n + lr) * 2));
                *(bf16_t*)((char*)Pl + wave * 2048 + A) = (bf16_t)p;
            }
        }
        #pragma unroll
        for (int r = 0; r < 4; ++r) {
            float s = rowsum[r];
            s += __shfl_xor(s, 1);
            s += __shfl_xor(s, 2);
            s += __shfl_xor(s, 4);
            s += __shfl_xor(s, 8);
            lrun[r] += s;
        }

        // ---- O += P * V ----
        __builtin_amdgcn_s_setprio(1);
        #pragma unroll
        for (int n = 0; n < 8; ++n) {
            f32x4 a = oacc[n];
            #pragma unroll
            for (int kk = 0; kk < 2; ++kk) {
                const uint32_t Ap = pl_swz((uint32_t)(lr * 128 + (32 * kk + k0) * 2));
                bf16x8 pf = *(const bf16x8*)((const char*)Pl + wave * 2048 + Ap);
                const uint32_t Av = vt_swz((uint32_t)((16 * n + lr) * 128 + 64 * kk + 16 * lk));
                bf16x8 vf = *(const bf16x8*)((const char*)Vt + Av);
                a = __builtin_amdgcn_mfma_f32_16x16x32_bf16(pf, vf, a, 0, 0, 0);
            }
            oacc[n] = a;
        }
        __builtin_amdgcn_s_setprio(0);
        __syncthreads();
    }

    // ---- epilogue ----
    float* obase = out + bh_off + (size_t)(qi * 64 + wave * 16) * ROWSTRIDE;
    #pragma unroll
    for (int r = 0; r < 4; ++r) {
        const float inv = 1.0f / lrun[r];
        float* orow = obase + (size_t)(4 * lk + r) * ROWSTRIDE;
        #pragma unroll
        for (int n = 0; n < 8; ++n) {
            orow[16 * n + lr] = oacc[n][r] * inv;
        }
    }
}

extern "C" void kernel_launch(void* const* d_in, const int* in_sizes, int n_in,
                              void* d_out, int out_size, void* d_ws, size_t ws_size,
                              hipStream_t stream) {
    const float* q = (const float*)d_in[0];
    const float* k = (const float*)d_in[1];
    const float* v = (const float*)d_in[2];
    float* out = (float*)d_out;
    sparse_attn_kernel<<<dim3(2048), dim3(256), 0, stream>>>(q, k, v, out);
}

// Round 7
// 115.891 us; speedup vs baseline: 4.5422x; 1.6614x over previous
//
#include <hip/hip_runtime.h>
#include <hip/hip_bf16.h>

// Block-sparse attention: B=2, S=4096, H=16, D=128, BS=64, LOCAL=8, GLOBAL=1.
// fp32 in/out, bf16 MFMA, flash online softmax (exp2 domain).
// Round 7: non-overlapping kreg/vreg live ranges (peak prefetch 32 VGPR, was
// 64) to get VGPR_Count <= 128 (round 6: 136 -> 3 waves/SIMD, occupancy
// halved). V loaded same-iteration (latency hidden under barrier+QK); K
// prefetched one iteration ahead (hidden under softmax+PV+next stage).
// lrun reduce deferred to epilogue.

typedef __bf16 bf16_t;
typedef bf16_t bf16x8 __attribute__((ext_vector_type(8)));
typedef bf16_t bf16x4 __attribute__((ext_vector_type(4)));
typedef float f32x4 __attribute__((ext_vector_type(4)));

#define BSZ 64
#define DIM 128
#define NH 16
#define SEQ 4096
#define ROWSTRIDE (NH * DIM)

// Kb: [64][128] bf16, A = row*256 + col*2. Fold row low-3 bits into chunk bits.
__device__ __forceinline__ uint32_t kb_swz(uint32_t A) {
    return A ^ (((A >> 8) & 7u) << 4);
}
// Vt: [128][64] bf16, A = d*128 + k*2. Fold d bits so PV read (lanes vary d)
// spreads over 8 chunk slots per 16-lane phase.
__device__ __forceinline__ uint32_t vt_swz(uint32_t A) {
    return A ^ (((A >> 9) & 7u) << 4) ^ (((A >> 8) & 1u) << 6);
}
// Pl: per-wave [16][64] bf16, A = row*128 + col*2. Fold row low-3 bits.
__device__ __forceinline__ uint32_t pl_swz(uint32_t A) {
    return A ^ (((A >> 7) & 7u) << 4);
}

__global__ __launch_bounds__(256) void sparse_attn_kernel(
    const float* __restrict__ q, const float* __restrict__ k,
    const float* __restrict__ v, float* __restrict__ out)
{
    __shared__ __align__(16) bf16_t Kb[BSZ * DIM];      // 16384 B
    __shared__ __align__(16) bf16_t Vt[DIM * BSZ];      // 16384 B
    __shared__ __align__(16) bf16_t Pl[4 * 16 * 64];    //  8192 B  (total 40960)

    // XCD-aware swizzle: 2048 wgs, 8 XCDs -> contiguous 256-chunk per XCD.
    const int L  = ((blockIdx.x & 7) << 8) | (blockIdx.x >> 3);
    const int qi = L & 63;
    const int h  = (L >> 6) & 15;
    const int b  = L >> 10;

    const int tid  = threadIdx.x;
    const int wave = tid >> 6;
    const int lane = tid & 63;
    const int lr = lane & 15;
    const int lk = lane >> 4;
    const int k0 = lk * 8;

    const int sc4 = tid & 31;   // staging: float4 column 0..31
    const int sr  = tid >> 5;   // staging: row group 0..7

    const float scale2 = 0.12751649736230476f;  // (1/sqrt(128)) * log2(e)

    const size_t bh_off = ((size_t)b * SEQ * NH + (size_t)h) * DIM;
    const float* kbh = k + bh_off;
    const float* vbh = v + bh_off;

    // ---- Q fragments, pre-scaled (wave owns q rows [qi*64+wave*16, +16)) ----
    bf16x8 qf[4];
    {
        const float* qrow = q + bh_off + (size_t)(qi * 64 + wave * 16 + lr) * ROWSTRIDE;
        #pragma unroll
        for (int kk = 0; kk < 4; ++kk) {
            const float4 a0 = *(const float4*)(qrow + 32 * kk + k0);
            const float4 a1 = *(const float4*)(qrow + 32 * kk + k0 + 4);
            bf16x8 f;
            f[0] = (bf16_t)(a0.x * scale2); f[1] = (bf16_t)(a0.y * scale2);
            f[2] = (bf16_t)(a0.z * scale2); f[3] = (bf16_t)(a0.w * scale2);
            f[4] = (bf16_t)(a1.x * scale2); f[5] = (bf16_t)(a1.y * scale2);
            f[6] = (bf16_t)(a1.z * scale2); f[7] = (bf16_t)(a1.w * scale2);
            qf[kk] = f;
        }
    }

    f32x4 oacc[8];
    #pragma unroll
    for (int n = 0; n < 8; ++n) oacc[n] = (f32x4){0.f, 0.f, 0.f, 0.f};
    float mrun[4], lrun[4];
    #pragma unroll
    for (int r = 0; r < 4; ++r) { mrun[r] = -3.0e38f; lrun[r] = 0.f; }

    const int nnz = (qi < 8) ? (qi + 1) : 9;

    float4 kreg[8];   // K row (8i+sr), cols 4*sc4..+3   (one iter ahead)
    float4 vreg[8];   // V row 4*(sr+8*T)+i, cols 4*sc4..+3  (same iter)

    #define LOAD_K(jb)                                                            \
    {                                                                             \
        const float* kb_ = kbh + (size_t)((jb) * 64) * ROWSTRIDE + 4 * sc4;       \
        _Pragma("unroll")                                                         \
        for (int i = 0; i < 8; ++i)                                               \
            kreg[i] = *(const float4*)(kb_ + (size_t)(8 * i + sr) * ROWSTRIDE);   \
    }
    #define LOAD_V(jb)                                                            \
    {                                                                             \
        const float* vb_ = vbh + (size_t)((jb) * 64) * ROWSTRIDE + 4 * sc4;       \
        _Pragma("unroll")                                                         \
        for (int T = 0; T < 2; ++T)                                               \
            _Pragma("unroll")                                                     \
            for (int i = 0; i < 4; ++i)                                           \
                vreg[T * 4 + i] = *(const float4*)(vb_ +                          \
                    (size_t)(4 * (sr + 8 * T) + i) * ROWSTRIDE);                  \
    }

    LOAD_K(0);  // j_of(0) == 0 for every qi

    for (int t = 0; t < nnz; ++t) {
        const int j = (qi < 8) ? t : ((t == 0) ? 0 : (qi - 8 + t));

        // ---- issue V loads for THIS block (consumed after QK^T below) ----
        LOAD_V(j);

        // ---- Kb write from kreg (counted vmcnt waits only the K loads) ----
        #pragma unroll
        for (int i = 0; i < 8; ++i) {
            const float4 t4 = kreg[i];
            bf16x4 c = {(bf16_t)t4.x, (bf16_t)t4.y, (bf16_t)t4.z, (bf16_t)t4.w};
            const uint32_t A = kb_swz((uint32_t)((8 * i + sr) * 256 + 8 * sc4));
            *(bf16x4*)((char*)Kb + A) = c;
        }
        __syncthreads();

        // ---- S = Q*K^T (16x64 per wave), already in exp2 domain ----
        f32x4 sacc[4];
        __builtin_amdgcn_s_setprio(1);
        #pragma unroll
        for (int n = 0; n < 4; ++n) {
            f32x4 a = (f32x4){0.f, 0.f, 0.f, 0.f};
            #pragma unroll
            for (int kk = 0; kk < 4; ++kk) {
                const uint32_t A = kb_swz((uint32_t)((16 * n + lr) * 256 + 64 * kk + 16 * lk));
                bf16x8 kf = *(const bf16x8*)((const char*)Kb + A);
                a = __builtin_amdgcn_mfma_f32_16x16x32_bf16(qf[kk], kf, a, 0, 0, 0);
            }
            sacc[n] = a;
        }
        __builtin_amdgcn_s_setprio(0);

        // ---- Vt write from vreg (vreg dies here; kreg issue comes after) ----
        #pragma unroll
        for (int T = 0; T < 2; ++T) {
            #pragma unroll
            for (int j2 = 0; j2 < 4; ++j2) {
                const int d = 4 * sc4 + j2;
                bf16x4 c = {(bf16_t)((const float*)&vreg[T * 4 + 0])[j2],
                            (bf16_t)((const float*)&vreg[T * 4 + 1])[j2],
                            (bf16_t)((const float*)&vreg[T * 4 + 2])[j2],
                            (bf16_t)((const float*)&vreg[T * 4 + 3])[j2]};
                const uint32_t A = vt_swz((uint32_t)(d * 128 + 8 * (sr + 8 * T)));
                *(bf16x4*)((char*)Vt + A) = c;
            }
        }

        // ---- issue next K loads (hidden under softmax + PV + next stage) ----
        if (t + 1 < nnz) {
            const int jn = (qi < 8) ? (t + 1) : (qi - 8 + t + 1);
            LOAD_K(jn);
        }

        // ---- mask (diag only) + row max ----
        float vmax[4];
        #pragma unroll
        for (int r = 0; r < 4; ++r) vmax[r] = -3.0e38f;
        if (j == qi) {
            #pragma unroll
            for (int n = 0; n < 4; ++n)
                #pragma unroll
                for (int r = 0; r < 4; ++r) {
                    float s = sacc[n][r];
                    const int col  = 16 * n + lr;
                    const int rowq = wave * 16 + 4 * lk + r;
                    if (col > rowq) s = -1.0e30f;
                    sacc[n][r] = s;
                    vmax[r] = fmaxf(vmax[r], s);
                }
        } else {
            #pragma unroll
            for (int n = 0; n < 4; ++n)
                #pragma unroll
                for (int r = 0; r < 4; ++r)
                    vmax[r] = fmaxf(vmax[r], sacc[n][r]);
        }
        #pragma unroll
        for (int r = 0; r < 4; ++r) {
            float m = vmax[r];
            m = fmaxf(m, __shfl_xor(m, 1));
            m = fmaxf(m, __shfl_xor(m, 2));
            m = fmaxf(m, __shfl_xor(m, 4));
            m = fmaxf(m, __shfl_xor(m, 8));
            vmax[r] = m;
        }

        // ---- online softmax (defer-max THR=8 log2; lrun kept per-lane) ----
        bool defer = true;
        #pragma unroll
        for (int r = 0; r < 4; ++r) defer &= (vmax[r] - mrun[r] <= 8.0f);
        if (!__all(defer)) {
            #pragma unroll
            for (int r = 0; r < 4; ++r) {
                const float mnew = fmaxf(mrun[r], vmax[r]);
                const float alpha = exp2f(mrun[r] - mnew);
                mrun[r] = mnew;
                lrun[r] *= alpha;
                #pragma unroll
                for (int n = 0; n < 8; ++n) oacc[n][r] *= alpha;
            }
        }
        #pragma unroll
        for (int n = 0; n < 4; ++n) {
            #pragma unroll
            for (int r = 0; r < 4; ++r) {
                const float p = exp2f(sacc[n][r] - mrun[r]);
                lrun[r] += p;   // per-lane partial; reduced in epilogue
                const uint32_t A = pl_swz((uint32_t)((4 * lk + r) * 128 + (16 * n + lr) * 2));
                *(bf16_t*)((char*)Pl + wave * 2048 + A) = (bf16_t)p;
            }
        }
        __syncthreads();

        // ---- O += P * V ----
        __builtin_amdgcn_s_setprio(1);
        #pragma unroll
        for (int n = 0; n < 8; ++n) {
            f32x4 a = oacc[n];
            #pragma unroll
            for (int kk = 0; kk < 2; ++kk) {
                const uint32_t Ap = pl_swz((uint32_t)(lr * 128 + (32 * kk + k0) * 2));
                bf16x8 pf = *(const bf16x8*)((const char*)Pl + wave * 2048 + Ap);
                const uint32_t Av = vt_swz((uint32_t)((16 * n + lr) * 128 + 64 * kk + 16 * lk));
                bf16x8 vf = *(const bf16x8*)((const char*)Vt + Av);
                a = __builtin_amdgcn_mfma_f32_16x16x32_bf16(pf, vf, a, 0, 0, 0);
            }
            oacc[n] = a;
        }
        __builtin_amdgcn_s_setprio(0);
    }

    // ---- epilogue: reduce lrun across the 16-lane row group, then store ----
    float* obase = out + bh_off + (size_t)(qi * 64 + wave * 16) * ROWSTRIDE;
    #pragma unroll
    for (int r = 0; r < 4; ++r) {
        float s = lrun[r];
        s += __shfl_xor(s, 1);
        s += __shfl_xor(s, 2);
        s += __shfl_xor(s, 4);
        s += __shfl_xor(s, 8);
        const float inv = 1.0f / s;
        float* orow = obase + (size_t)(4 * lk + r) * ROWSTRIDE;
        #pragma unroll
        for (int n = 0; n < 8; ++n) {
            orow[16 * n + lr] = oacc[n][r] * inv;
        }
    }
}

extern "C" void kernel_launch(void* const* d_in, const int* in_sizes, int n_in,
                              void* d_out, int out_size, void* d_ws, size_t ws_size,
                              hipStream_t stream) {
    const float* q = (const float*)d_in[0];
    const float* k = (const float*)d_in[1];
    const float* v = (const float*)d_in[2];
    float* out = (float*)d_out;
    sparse_attn_kernel<<<dim3(2048), dim3(256), 0, stream>>>(q, k, v, out);
}

// Round 8
// 105.539 us; speedup vs baseline: 4.9877x; 1.0981x over previous
//
#include <hip/hip_runtime.h>
#include <hip/hip_bf16.h>

// Block-sparse attention: B=2, S=4096, H=16, D=128, BS=64, LOCAL=8, GLOBAL=1.
// fp32 in/out, bf16 MFMA, flash online softmax (exp2 domain).
// Round 8: swapped QK^T (mfma(K,Q) -> lane owns a full q-row of S^T) +
// in-register softmax + register P-exchange for the PV A-fragment.
// Pl LDS eliminated (LDS 40960 -> 32768). Same staging/barrier skeleton as r7.

typedef __bf16 bf16_t;
typedef bf16_t bf16x8 __attribute__((ext_vector_type(8)));
typedef bf16_t bf16x4 __attribute__((ext_vector_type(4)));
typedef float f32x4 __attribute__((ext_vector_type(4)));
typedef uint32_t u32x4 __attribute__((ext_vector_type(4)));

#define BSZ 64
#define DIM 128
#define NH 16
#define SEQ 4096
#define ROWSTRIDE (NH * DIM)

// Kb: [64][128] bf16, A = row*256 + col*2. Fold row low-3 bits into chunk bits.
__device__ __forceinline__ uint32_t kb_swz(uint32_t A) {
    return A ^ (((A >> 8) & 7u) << 4);
}
// Vt: [128][64] bf16, A = d*128 + k*2. Fold d bits so PV read (lanes vary d)
// spreads over 8 chunk slots per 16-lane phase.
__device__ __forceinline__ uint32_t vt_swz(uint32_t A) {
    return A ^ (((A >> 9) & 7u) << 4) ^ (((A >> 8) & 1u) << 6);
}

__global__ __launch_bounds__(256) void sparse_attn_kernel(
    const float* __restrict__ q, const float* __restrict__ k,
    const float* __restrict__ v, float* __restrict__ out)
{
    __shared__ __align__(16) bf16_t Kb[BSZ * DIM];      // 16384 B
    __shared__ __align__(16) bf16_t Vt[DIM * BSZ];      // 16384 B (total 32768)

    // XCD-aware swizzle: 2048 wgs, 8 XCDs -> contiguous 256-chunk per XCD.
    const int L  = ((blockIdx.x & 7) << 8) | (blockIdx.x >> 3);
    const int qi = L & 63;
    const int h  = (L >> 6) & 15;
    const int b  = L >> 10;

    const int tid  = threadIdx.x;
    const int wave = tid >> 6;
    const int lane = tid & 63;
    const int lr = lane & 15;
    const int lk = lane >> 4;
    const int k0 = lk * 8;

    const int sc4 = tid & 31;   // staging: float4 column 0..31
    const int sr  = tid >> 5;   // staging: row group 0..7

    const float scale2 = 0.12751649736230476f;  // (1/sqrt(128)) * log2(e)

    const size_t bh_off = ((size_t)b * SEQ * NH + (size_t)h) * DIM;
    const float* kbh = k + bh_off;
    const float* vbh = v + bh_off;

    // ---- Q fragments, pre-scaled (wave owns q rows [qi*64+wave*16, +16)) ----
    bf16x8 qf[4];
    {
        const float* qrow = q + bh_off + (size_t)(qi * 64 + wave * 16 + lr) * ROWSTRIDE;
        #pragma unroll
        for (int kk = 0; kk < 4; ++kk) {
            const float4 a0 = *(const float4*)(qrow + 32 * kk + k0);
            const float4 a1 = *(const float4*)(qrow + 32 * kk + k0 + 4);
            bf16x8 f;
            f[0] = (bf16_t)(a0.x * scale2); f[1] = (bf16_t)(a0.y * scale2);
            f[2] = (bf16_t)(a0.z * scale2); f[3] = (bf16_t)(a0.w * scale2);
            f[4] = (bf16_t)(a1.x * scale2); f[5] = (bf16_t)(a1.y * scale2);
            f[6] = (bf16_t)(a1.z * scale2); f[7] = (bf16_t)(a1.w * scale2);
            qf[kk] = f;
        }
    }

    f32x4 oacc[8];
    #pragma unroll
    for (int n = 0; n < 8; ++n) oacc[n] = (f32x4){0.f, 0.f, 0.f, 0.f};
    float mrun = -3.0e38f, lrun = 0.f;   // per-lane: this lane's q-row is lr

    const int qrow_local = wave * 16 + lr;  // q position within the 64-block
    const int nnz = (qi < 8) ? (qi + 1) : 9;

    float4 kreg[8];   // K row (8i+sr), cols 4*sc4..+3   (one iter ahead)
    float4 vreg[8];   // V row 4*(sr+8*T)+i, cols 4*sc4..+3  (same iter)

    #define LOAD_K(jb)                                                            \
    {                                                                             \
        const float* kb_ = kbh + (size_t)((jb) * 64) * ROWSTRIDE + 4 * sc4;       \
        _Pragma("unroll")                                                         \
        for (int i = 0; i < 8; ++i)                                               \
            kreg[i] = *(const float4*)(kb_ + (size_t)(8 * i + sr) * ROWSTRIDE);   \
    }
    #define LOAD_V(jb)                                                            \
    {                                                                             \
        const float* vb_ = vbh + (size_t)((jb) * 64) * ROWSTRIDE + 4 * sc4;       \
        _Pragma("unroll")                                                         \
        for (int T = 0; T < 2; ++T)                                               \
            _Pragma("unroll")                                                     \
            for (int i = 0; i < 4; ++i)                                           \
                vreg[T * 4 + i] = *(const float4*)(vb_ +                          \
                    (size_t)(4 * (sr + 8 * T) + i) * ROWSTRIDE);                  \
    }

    LOAD_K(0);  // j_of(0) == 0 for every qi

    for (int t = 0; t < nnz; ++t) {
        const int j = (qi < 8) ? t : ((t == 0) ? 0 : (qi - 8 + t));

        // ---- issue V loads for THIS block (consumed after QK^T below) ----
        LOAD_V(j);

        // ---- Kb write from kreg ----
        #pragma unroll
        for (int i = 0; i < 8; ++i) {
            const float4 t4 = kreg[i];
            bf16x4 c = {(bf16_t)t4.x, (bf16_t)t4.y, (bf16_t)t4.z, (bf16_t)t4.w};
            const uint32_t A = kb_swz((uint32_t)((8 * i + sr) * 256 + 8 * sc4));
            *(bf16x4*)((char*)Kb + A) = c;
        }
        __syncthreads();

        // ---- S^T = K*Q^T: lane holds S[k=16n+4lk+r][q=lr] (exp2 domain) ----
        f32x4 sacc[4];
        __builtin_amdgcn_s_setprio(1);
        #pragma unroll
        for (int n = 0; n < 4; ++n) {
            f32x4 a = (f32x4){0.f, 0.f, 0.f, 0.f};
            #pragma unroll
            for (int kk = 0; kk < 4; ++kk) {
                const uint32_t A = kb_swz((uint32_t)((16 * n + lr) * 256 + 64 * kk + 16 * lk));
                bf16x8 kf = *(const bf16x8*)((const char*)Kb + A);
                a = __builtin_amdgcn_mfma_f32_16x16x32_bf16(kf, qf[kk], a, 0, 0, 0);
            }
            sacc[n] = a;
        }
        __builtin_amdgcn_s_setprio(0);

        // ---- Vt write from vreg (vreg dies here) ----
        #pragma unroll
        for (int T = 0; T < 2; ++T) {
            #pragma unroll
            for (int j2 = 0; j2 < 4; ++j2) {
                const int d = 4 * sc4 + j2;
                bf16x4 c = {(bf16_t)((const float*)&vreg[T * 4 + 0])[j2],
                            (bf16_t)((const float*)&vreg[T * 4 + 1])[j2],
                            (bf16_t)((const float*)&vreg[T * 4 + 2])[j2],
                            (bf16_t)((const float*)&vreg[T * 4 + 3])[j2]};
                const uint32_t A = vt_swz((uint32_t)(d * 128 + 8 * (sr + 8 * T)));
                *(bf16x4*)((char*)Vt + A) = c;
            }
        }

        // ---- mask (diag only) + row max (in-lane + 2 shfl) ----
        if (j == qi) {
            #pragma unroll
            for (int n = 0; n < 4; ++n)
                #pragma unroll
                for (int r = 0; r < 4; ++r) {
                    if (16 * n + 4 * lk + r > qrow_local) sacc[n][r] = -1.0e30f;
                }
        }
        float vmax = -3.0e38f;
        #pragma unroll
        for (int n = 0; n < 4; ++n)
            #pragma unroll
            for (int r = 0; r < 4; ++r) vmax = fmaxf(vmax, sacc[n][r]);
        vmax = fmaxf(vmax, __shfl_xor(vmax, 16));
        vmax = fmaxf(vmax, __shfl_xor(vmax, 32));

        // ---- online softmax (defer-max THR=8 log2), fully in-register ----
        if (!__all(vmax - mrun <= 8.0f)) {
            const float mnew = fmaxf(mrun, vmax);
            const float alpha = exp2f(mrun - mnew);
            mrun = mnew;
            lrun *= alpha;
            float av[4];
            #pragma unroll
            for (int r = 0; r < 4; ++r) av[r] = __shfl(alpha, 4 * lk + r);
            #pragma unroll
            for (int n = 0; n < 8; ++n)
                #pragma unroll
                for (int r = 0; r < 4; ++r) oacc[n][r] *= av[r];
        }
        // p + pack to bf16 chunks: ch[2n],ch[2n+1] = P[q=lr][k=16n+4lk + 0..3]
        uint32_t ch[8];
        #pragma unroll
        for (int n = 0; n < 4; ++n) {
            float p0 = exp2f(sacc[n][0] - mrun);
            float p1 = exp2f(sacc[n][1] - mrun);
            float p2 = exp2f(sacc[n][2] - mrun);
            float p3 = exp2f(sacc[n][3] - mrun);
            lrun += (p0 + p1) + (p2 + p3);
            bf16x4 c4 = {(bf16_t)p0, (bf16_t)p1, (bf16_t)p2, (bf16_t)p3};
            uint32_t* cw = (uint32_t*)&c4;
            ch[2 * n]     = cw[0];
            ch[2 * n + 1] = cw[1];
        }

        // ---- register exchange: build PV A-frags P[q=lr][k=32kk+8lk..+7] ----
        // dest (lr,lk) takes chunk[2kk+(lk>>1)] from lane lr+32*(lk&1)+16*delta
        bf16x8 paf[2];
        {
            const int s0 = lr + 32 * (lk & 1);
            const bool hi = (lk & 2) != 0;
            #pragma unroll
            for (int kk = 0; kk < 2; ++kk) {
                uint32_t res[4];
                #pragma unroll
                for (int u = 0; u < 2; ++u) {
                    const uint32_t a0 = (uint32_t)__shfl((int)ch[4 * kk + u],     s0);
                    const uint32_t b0 = (uint32_t)__shfl((int)ch[4 * kk + 2 + u], s0);
                    const uint32_t a1 = (uint32_t)__shfl((int)ch[4 * kk + u],     s0 + 16);
                    const uint32_t b1 = (uint32_t)__shfl((int)ch[4 * kk + 2 + u], s0 + 16);
                    res[u]     = hi ? b0 : a0;
                    res[2 + u] = hi ? b1 : a1;
                }
                u32x4 tv = {res[0], res[1], res[2], res[3]};
                paf[kk] = *(bf16x8*)&tv;
            }
        }

        // ---- issue next K loads (kreg was dead through the exchange) ----
        if (t + 1 < nnz) {
            const int jn = (qi < 8) ? (t + 1) : (qi - 8 + t + 1);
            LOAD_K(jn);
        }
        __syncthreads();   // QK's Kb reads done before next iter's Kb write

        // ---- O += P * V ----
        __builtin_amdgcn_s_setprio(1);
        #pragma unroll
        for (int n = 0; n < 8; ++n) {
            f32x4 a = oacc[n];
            #pragma unroll
            for (int kk = 0; kk < 2; ++kk) {
                const uint32_t Av = vt_swz((uint32_t)((16 * n + lr) * 128 + 64 * kk + 16 * lk));
                bf16x8 vf = *(const bf16x8*)((const char*)Vt + Av);
                a = __builtin_amdgcn_mfma_f32_16x16x32_bf16(paf[kk], vf, a, 0, 0, 0);
            }
            oacc[n] = a;
        }
        __builtin_amdgcn_s_setprio(0);
    }

    // ---- epilogue: total l per q-row, redistribute to oacc rows, store ----
    float lrtot = lrun;
    lrtot += __shfl_xor(lrtot, 16);
    lrtot += __shfl_xor(lrtot, 32);
    float* obase = out + bh_off + (size_t)(qi * 64 + wave * 16) * ROWSTRIDE;
    #pragma unroll
    for (int r = 0; r < 4; ++r) {
        const float inv = 1.0f / __shfl(lrtot, 4 * lk + r);
        float* orow = obase + (size_t)(4 * lk + r) * ROWSTRIDE;
        #pragma unroll
        for (int n = 0; n < 8; ++n) {
            orow[16 * n + lr] = oacc[n][r] * inv;
        }
    }
}

extern "C" void kernel_launch(void* const* d_in, const int* in_sizes, int n_in,
                              void* d_out, int out_size, void* d_ws, size_t ws_size,
                              hipStream_t stream) {
    const float* q = (const float*)d_in[0];
    const float* k = (const float*)d_in[1];
    const float* v = (const float*)d_in[2];
    float* out = (float*)d_out;
    sparse_attn_kernel<<<dim3(2048), dim3(256), 0, stream>>>(q, k, v, out);
}